// Round 2
// baseline (2660.127 us; speedup 1.0000x reference)
//
#include <hip/hip_runtime.h>
#include <math.h>

typedef unsigned short u16;   // raw bf16 bits

#define BB 4
#define CC 256
#define HH 128
#define WW2 128
#define HW 16384
#define PTOT 65536
#define CHD 128
#define HID 680
#define HID2 1360
#define LN_EPS 1e-6f

#define BM 128
#define BN 128
#define BK 8

#define MODE_PLAIN 0
#define MODE_AV 1
#define MODE_FFNOUT 2

__device__ __forceinline__ float b2f(u16 u) {
    return __uint_as_float(((unsigned int)u) << 16);
}
__device__ __forceinline__ u16 f2b(float f) {
    unsigned int x = __float_as_uint(f);
    x += 0x7fffu + ((x >> 16) & 1u);        // round-to-nearest-even
    return (u16)(x >> 16);
}
__device__ __forceinline__ float4 loadv4(const float* p) { return *(const float4*)p; }
__device__ __forceinline__ float4 loadv4(const u16* p) {
    ushort4 u = *(const ushort4*)p;
    return make_float4(b2f(u.x), b2f(u.y), b2f(u.z), b2f(u.w));
}
__device__ __forceinline__ void storev4(float* p, float4 v) { *(float4*)p = v; }
__device__ __forceinline__ void storev4(u16* p, float4 v) {
    *(ushort4*)p = make_ushort4(f2b(v.x), f2b(v.y), f2b(v.z), f2b(v.w));
}

// ---------------- zero fill (graph-capture-safe) -------------------------------
__global__ __launch_bounds__(256) void k_zero(float* __restrict__ p, int n) {
    int i = blockIdx.x * 256 + threadIdx.x;
    if (i < n) p[i] = 0.f;
}

// ---------------- LN stats: per-pixel mean & rstd over C=256 channels ----------
__global__ __launch_bounds__(256) void k_ln_stats(const float* __restrict__ src,
                                                  float* __restrict__ mu,
                                                  float* __restrict__ rs) {
    int p = blockIdx.x * 256 + threadIdx.x;        // 0..PTOT
    int b = p >> 14, hw = p & 16383;
    const float* base = src + ((size_t)b * CC) * HW + hw;
    float s = 0.f, s2 = 0.f;
#pragma unroll 8
    for (int c = 0; c < CC; ++c) {
        float v = base[(size_t)c * HW];
        s += v; s2 += v * v;
    }
    float m = s * (1.f / CC);
    float var = fmaxf(s2 * (1.f / CC) - m * m, 0.f);
    mu[p] = m;
    rs[p] = rsqrtf(var + LN_EPS);
}

// ---------------- generic 1x1-conv GEMM: out[o,p] = bias[o] + sum_c W[o,c]*A(c,p)
template <typename TA, typename TO, int MODE>
__global__ __launch_bounds__(256)
void k_gemm(const TA* __restrict__ src, int cin,
            const float* __restrict__ Wm, const float* __restrict__ bias,
            const float* __restrict__ lnw, const float* __restrict__ lnb,
            const float* __restrict__ mu, const float* __restrict__ rs,
            const float* __restrict__ res,
            TO* __restrict__ out, int cout) {
    __shared__ float sA[BK][BN];
    __shared__ float sW[BK][BM];

    const int tid = threadIdx.x;
    const int tx = tid & 15;
    const int ty = tid >> 4;

    size_t src_off = 0, out_off = 0;
    const float* Wp = Wm;
    if (MODE == MODE_AV) {
        int z = blockIdx.z, b = z >> 1, h = z & 1;
        src_off = ((size_t)b * 512 + 256 + (size_t)h * CHD) * HW;   // v part of kv
        out_off = ((size_t)b * CC + (size_t)h * CHD) * HW;
        Wp = Wm + (size_t)z * CHD * CHD;
    }

    const int j0 = blockIdx.x * BN;        // pixel tile start
    const int o0 = blockIdx.y * BM;        // out-channel tile start
    const int bfold = j0 >> 14;            // batch fold for (B,C,HW) layouts
    const int hw0 = j0 & 16383;
    const TA* sbase = src + src_off + (size_t)bfold * cin * HW + hw0;

    const bool lnA = (lnw != nullptr) && (MODE != MODE_FFNOUT);

    float acc[8][8];
#pragma unroll
    for (int i = 0; i < 8; ++i)
#pragma unroll
        for (int j = 0; j < 8; ++j) acc[i][j] = 0.f;

    const int r = tid >> 5;                // 0..7  (k row)
    const int q4 = (tid & 31) * 4;         // 0..124

    for (int k0 = 0; k0 < cin; k0 += BK) {
        // stage A tile (BK x BN), LN applied on the fly
        {
            int c = k0 + r;
            float4 v = loadv4(sbase + (size_t)c * HW + q4);
            if (lnA) {
                float4 mm = *(const float4*)(mu + j0 + q4);
                float4 rr = *(const float4*)(rs + j0 + q4);
                float wgt = lnw[c], bb = lnb[c];
                v.x = (v.x - mm.x) * rr.x * wgt + bb;
                v.y = (v.y - mm.y) * rr.y * wgt + bb;
                v.z = (v.z - mm.z) * rr.z * wgt + bb;
                v.w = (v.w - mm.w) * rr.w * wgt + bb;
            }
            *(float4*)&sA[r][q4] = v;
        }
        // stage W tile (BK x BM), guarded for ragged cout (1360)
        {
            int c = k0 + r;
            int o = o0 + q4;
            float4 wv;
            wv.x = (o + 0 < cout) ? Wp[(size_t)(o + 0) * cin + c] : 0.f;
            wv.y = (o + 1 < cout) ? Wp[(size_t)(o + 1) * cin + c] : 0.f;
            wv.z = (o + 2 < cout) ? Wp[(size_t)(o + 2) * cin + c] : 0.f;
            wv.w = (o + 3 < cout) ? Wp[(size_t)(o + 3) * cin + c] : 0.f;
            *(float4*)&sW[r][q4] = wv;
        }
        __syncthreads();
#pragma unroll
        for (int k = 0; k < BK; ++k) {
            float a[8], w[8];
            *(float4*)&a[0] = *(const float4*)&sA[k][tx * 4];
            *(float4*)&a[4] = *(const float4*)&sA[k][tx * 4 + 64];
            *(float4*)&w[0] = *(const float4*)&sW[k][ty * 4];
            *(float4*)&w[4] = *(const float4*)&sW[k][ty * 4 + 64];
#pragma unroll
            for (int i = 0; i < 8; ++i)
#pragma unroll
                for (int j = 0; j < 8; ++j) acc[i][j] += w[i] * a[j];
        }
        __syncthreads();
    }

    // epilogue
    for (int i = 0; i < 8; ++i) {
        int o = o0 + ty * 4 + (i & 3) + ((i >> 2) << 6);
        if (o >= cout) continue;
        float bo = bias ? bias[o] : 0.f;
        size_t rowbase = out_off + ((size_t)bfold * cout + o) * HW + hw0;
#pragma unroll
        for (int half = 0; half < 2; ++half) {
            int jj = tx * 4 + half * 64;
            size_t addr = rowbase + jj;
            float4 v;
            v.x = acc[i][half * 4 + 0] + bo;
            v.y = acc[i][half * 4 + 1] + bo;
            v.z = acc[i][half * 4 + 2] + bo;
            v.w = acc[i][half * 4 + 3] + bo;
            if (res) {
                float4 rv = *(const float4*)(res + addr);
                if (MODE == MODE_FFNOUT) {
                    float4 mm = *(const float4*)(mu + j0 + jj);
                    float4 rr = *(const float4*)(rs + j0 + jj);
                    float wgt = lnw[o], bb2 = lnb[o];
                    v.x += rv.x + ((rv.x - mm.x) * rr.x * wgt + bb2);
                    v.y += rv.y + ((rv.y - mm.y) * rr.y * wgt + bb2);
                    v.z += rv.z + ((rv.z - mm.z) * rr.z * wgt + bb2);
                    v.w += rv.w + ((rv.w - mm.w) * rr.w * wgt + bb2);
                } else {
                    v.x += rv.x; v.y += rv.y; v.z += rv.z; v.w += rv.w;
                }
            }
            storev4(out + addr, v);
        }
    }
}

// ---------------- L2-normalize 128-channel vectors per (b,head,pixel), in place --
__global__ __launch_bounds__(256) void k_l2norm(u16* __restrict__ buf, int chanPerBatch) {
    int p = blockIdx.x * 256 + threadIdx.x;    // B*HEADS*HW threads
    int hw = p & 16383;
    int bh = p >> 14;
    int b = bh >> 1, h = bh & 1;
    u16* base = buf + ((size_t)(b * chanPerBatch + h * CHD)) * HW + hw;
    float s = 0.f;
#pragma unroll 8
    for (int c = 0; c < CHD; ++c) {
        float v = b2f(base[(size_t)c * HW]);
        s += v * v;
    }
    float inv = 1.f / fmaxf(sqrtf(s), 1e-12f);
#pragma unroll 8
    for (int c = 0; c < CHD; ++c) {
        base[(size_t)c * HW] = f2b(b2f(base[(size_t)c * HW]) * inv);
    }
}

// ---------------- QK^T (channel attention), chunked reduction with atomics ------
#define DCH 512
__global__ __launch_bounds__(256) void k_attn_qk(const u16* __restrict__ qn,
                                                 const u16* __restrict__ kv,
                                                 float* __restrict__ attn) {
    int z = blockIdx.z, b = z >> 1, h = z & 1;
    const u16* qbase = qn + ((size_t)b * CC + (size_t)h * CHD) * HW;
    const u16* kbase = kv + ((size_t)b * 2 * CC + (size_t)h * CHD) * HW; // k half
    int d0 = blockIdx.x * DCH;
    __shared__ float sQ[8][CHD];
    __shared__ float sK[8][CHD];
    int tid = threadIdx.x;
    int tx = tid & 15, ty = tid >> 4;
    int ch = tid >> 1;
    int ds = (tid & 1) * 4;
    float acc[8][8];
#pragma unroll
    for (int i = 0; i < 8; ++i)
#pragma unroll
        for (int j = 0; j < 8; ++j) acc[i][j] = 0.f;

    for (int dd = 0; dd < DCH; dd += 8) {
        float4 qv = loadv4(qbase + (size_t)ch * HW + d0 + dd + ds);
        float4 kvv = loadv4(kbase + (size_t)ch * HW + d0 + dd + ds);
        sQ[ds + 0][ch] = qv.x;  sQ[ds + 1][ch] = qv.y;
        sQ[ds + 2][ch] = qv.z;  sQ[ds + 3][ch] = qv.w;
        sK[ds + 0][ch] = kvv.x; sK[ds + 1][ch] = kvv.y;
        sK[ds + 2][ch] = kvv.z; sK[ds + 3][ch] = kvv.w;
        __syncthreads();
#pragma unroll
        for (int k = 0; k < 8; ++k) {
            float qa[8], ka[8];
            *(float4*)&qa[0] = *(const float4*)&sQ[k][ty * 4];
            *(float4*)&qa[4] = *(const float4*)&sQ[k][ty * 4 + 64];
            *(float4*)&ka[0] = *(const float4*)&sK[k][tx * 4];
            *(float4*)&ka[4] = *(const float4*)&sK[k][tx * 4 + 64];
#pragma unroll
            for (int i = 0; i < 8; ++i)
#pragma unroll
                for (int j = 0; j < 8; ++j) acc[i][j] += qa[i] * ka[j];
        }
        __syncthreads();
    }
    float* abase = attn + (size_t)z * CHD * CHD;
    for (int i = 0; i < 8; ++i) {
        int ci = ty * 4 + (i & 3) + ((i >> 2) << 6);
        for (int j = 0; j < 8; ++j) {
            int cj = tx * 4 + (j & 3) + ((j >> 2) << 6);
            atomicAdd(&abase[(size_t)ci * CHD + cj], acc[i][j]);
        }
    }
}

// ---------------- scale + row softmax on (8,128,128) ---------------------------
__global__ __launch_bounds__(256) void k_softmax(float* __restrict__ attn,
                                                 const float* __restrict__ temp) {
    int row = blockIdx.x * 256 + threadIdx.x;   // 8*128 rows
    if (row >= 8 * CHD) return;
    int h = (row >> 7) & 1;
    float scale = 0.1f / (1.f + expf(-temp[h]));
    float* p = attn + (size_t)row * CHD;
    float m = -1e30f;
    for (int j = 0; j < CHD; ++j) m = fmaxf(m, p[j]);
    m *= scale;
    float s = 0.f;
    for (int j = 0; j < CHD; ++j) {
        float e = expf(p[j] * scale - m);
        p[j] = e; s += e;
    }
    float inv = 1.f / s;
    for (int j = 0; j < CHD; ++j) p[j] *= inv;
}

// ---------------- depthwise 3x3 + GELU-gate, per batch slab --------------------
__global__ __launch_bounds__(256) void k_dwgate(const u16* __restrict__ t,
                                                const float* __restrict__ dww,
                                                const float* __restrict__ dwb,
                                                u16* __restrict__ g) {
    int c = blockIdx.z;                        // 0..HID-1
    int x = blockIdx.x * 64 + threadIdx.x;     // W
    int yy = blockIdx.y * 4 + threadIdx.y;     // H
    const u16* t1 = t + (size_t)c * HW;
    const u16* t2 = t + (size_t)(c + HID) * HW;
    const float* w1 = dww + (size_t)c * 9;
    const float* w2 = dww + (size_t)(c + HID) * 9;
    float d1 = dwb[c], d2 = dwb[c + HID];
#pragma unroll
    for (int ky = 0; ky < 3; ++ky) {
        int sy = yy + ky - 1;
        if (sy < 0 || sy >= HH) continue;
#pragma unroll
        for (int kx = 0; kx < 3; ++kx) {
            int sx = x + kx - 1;
            if (sx < 0 || sx >= WW2) continue;
            float v1 = b2f(t1[sy * WW2 + sx]);
            float v2 = b2f(t2[sy * WW2 + sx]);
            d1 += v1 * w1[ky * 3 + kx];
            d2 += v2 * w2[ky * 3 + kx];
        }
    }
    float u = d1;
    float gl = 0.5f * u * (1.f + tanhf(0.7978845608028654f * (u + 0.044715f * u * u * u)));
    g[(size_t)c * HW + yy * WW2 + x] = f2b(gl * d2);
}

// -------------------------------------------------------------------------------
extern "C" void kernel_launch(void* const* d_in, const int* in_sizes, int n_in,
                              void* d_out, int out_size, void* d_ws, size_t ws_size,
                              hipStream_t stream) {
    const float* x     = (const float*)d_in[0];
    const float* y     = (const float*)d_in[1];
    const float* n1w   = (const float*)d_in[2];
    const float* n1b   = (const float*)d_in[3];
    const float* q_w   = (const float*)d_in[4];
    const float* q_b   = (const float*)d_in[5];
    const float* kv_w  = (const float*)d_in[6];
    const float* kv_b  = (const float*)d_in[7];
    const float* proj_w= (const float*)d_in[8];
    const float* proj_b= (const float*)d_in[9];
    const float* temp  = (const float*)d_in[10];
    const float* n2w   = (const float*)d_in[11];
    const float* n2b   = (const float*)d_in[12];
    const float* c1w   = (const float*)d_in[13];
    const float* c1b   = (const float*)d_in[14];
    const float* dww   = (const float*)d_in[15];
    const float* dwb   = (const float*)d_in[16];
    const float* c2w   = (const float*)d_in[17];
    const float* c2b   = (const float*)d_in[18];
    float* outf = (float*)d_out;

    // workspace layout (bytes):
    //   [0, 33.5MB)      qn slab  (bf16)  — later reused as ao, then g
    //   [33.5, 100.7MB)  kv slab  (bf16)  — later reused as t
    //   [100.7MB, ...)   fp32 stats (6 x PTOT) + attn (8*128*128)
    const size_t QN_BYTES = (size_t)BB * CC * HW * 2;        // 33,554,432
    const size_t KV_BYTES = QN_BYTES * 2;                    // 67,108,864
    const size_t NEED = QN_BYTES + KV_BYTES +
                        (size_t)6 * PTOT * 4 + (size_t)8 * CHD * CHD * 4;
    if (ws_size < NEED) return;   // undersized scratch: fail cleanly, don't fault

    char* wsb = (char*)d_ws;
    u16* qn   = (u16*)wsb;
    u16* kvb  = (u16*)(wsb + QN_BYTES);
    float* mu_x = (float*)(wsb + QN_BYTES + KV_BYTES);
    float* rs_x = mu_x + PTOT;
    float* mu_y = rs_x + PTOT;
    float* rs_y = mu_y + PTOT;
    float* mu2  = rs_y + PTOT;
    float* rs2  = mu2 + PTOT;
    float* attn = rs2 + PTOT;

    u16* ao = qn;    // reuse: q dead after QK^T
    u16* t  = kvb;   // reuse: kv dead after AV
    u16* g  = qn;    // reuse: ao dead after proj

    // LN stats for x and y
    k_ln_stats<<<PTOT / 256, 256, 0, stream>>>(x, mu_x, rs_x);
    k_ln_stats<<<PTOT / 256, 256, 0, stream>>>(y, mu_y, rs_y);

    // q = Wq * LN1(x) + bq ; kv = Wkv * LN1(y) + bkv
    k_gemm<float, u16, MODE_PLAIN><<<dim3(PTOT / BN, 2, 1), 256, 0, stream>>>(
        x, CC, q_w, q_b, n1w, n1b, mu_x, rs_x, nullptr, qn, CC);
    k_gemm<float, u16, MODE_PLAIN><<<dim3(PTOT / BN, 4, 1), 256, 0, stream>>>(
        y, CC, kv_w, kv_b, n1w, n1b, mu_y, rs_y, nullptr, kvb, 2 * CC);

    // L2 normalize q and k (per head, 128-channel vectors)
    k_l2norm<<<(BB * 2 * HW) / 256, 256, 0, stream>>>(qn, CC);
    k_l2norm<<<(BB * 2 * HW) / 256, 256, 0, stream>>>(kvb, 2 * CC);

    // attn = q·k^T (chunked, atomics), then scale+softmax
    k_zero<<<(8 * CHD * CHD) / 256, 256, 0, stream>>>(attn, 8 * CHD * CHD);
    k_attn_qk<<<dim3(HW / DCH, 1, 8), 256, 0, stream>>>(qn, kvb, attn);
    k_softmax<<<4, 256, 0, stream>>>(attn, temp);

    // ao = attn @ v   (ao overwrites q slab)
    k_gemm<u16, u16, MODE_AV><<<dim3(HW / BN, 1, 8), 256, 0, stream>>>(
        kvb, CHD, attn, nullptr, nullptr, nullptr, nullptr, nullptr, nullptr, ao, CHD);

    // y1 = y + proj(ao)   (y1 lives in d_out)
    k_gemm<u16, float, MODE_PLAIN><<<dim3(PTOT / BN, 2, 1), 256, 0, stream>>>(
        ao, CC, proj_w, proj_b, nullptr, nullptr, nullptr, nullptr, y, outf, CC);

    // LN stats for y1
    k_ln_stats<<<PTOT / 256, 256, 0, stream>>>(outf, mu2, rs2);

    // FFN per batch: t = conv1(LN2(y1)); g = gelu(dw1(t1))*dw2(t2);
    // out = conv2(g) + y1 + LN2(y1)   (in place over y1 in d_out)
    for (int b = 0; b < BB; ++b) {
        float* y1b = outf + (size_t)b * CC * HW;
        k_gemm<float, u16, MODE_PLAIN><<<dim3(HW / BN, (HID2 + BM - 1) / BM, 1), 256, 0, stream>>>(
            y1b, CC, c1w, c1b, n2w, n2b, mu2 + (size_t)b * HW, rs2 + (size_t)b * HW,
            nullptr, t, HID2);
        k_dwgate<<<dim3(WW2 / 64, HH / 4, HID), dim3(64, 4, 1), 0, stream>>>(t, dww, dwb, g);
        k_gemm<u16, float, MODE_FFNOUT><<<dim3(HW / BN, 2, 1), 256, 0, stream>>>(
            g, HID, c2w, c2b, n2w, n2b, mu2 + (size_t)b * HW, rs2 + (size_t)b * HW,
            y1b, y1b, CC);
    }
}

// Round 8
// 1211.084 us; speedup vs baseline: 2.1965x; 2.1965x over previous
//
#include <hip/hip_runtime.h>
#include <math.h>

typedef unsigned short u16;
typedef __attribute__((ext_vector_type(8))) short bf16x8;
typedef __attribute__((ext_vector_type(4))) float f32x4;

#define HW 16384
#define CHW (256*16384)

__device__ __forceinline__ float b2f(u16 u){ return __uint_as_float(((unsigned)u)<<16); }
__device__ __forceinline__ u16 f2b(float f){
  unsigned x = __float_as_uint(f);
  x += 0x7fffu + ((x>>16)&1u);          // RNE
  return (u16)(x>>16);
}
__device__ __forceinline__ void gload16(const u16* g, u16* l){
  __builtin_amdgcn_global_load_lds((const __attribute__((address_space(1))) unsigned int*)g,
                                   (__attribute__((address_space(3))) unsigned int*)l, 16, 0, 0);
}

// ---------------- weight fp32 -> bf16 with zero padding -------------------------
__global__ __launch_bounds__(256) void k_w2b(const float* __restrict__ src, u16* __restrict__ dst,
                                             int O, int K, int Kp) {
  int idx = blockIdx.x*256 + threadIdx.x;
  int o = idx / Kp, kk = idx - o*Kp;
  float v = (o < O && kk < K) ? src[(size_t)o*K + kk] : 0.f;
  dst[idx] = f2b(v);
}

// ---------------- fused LayerNorm + transpose to pixel-major bf16 ---------------
// src: fp32 channel-major [nb][256][16384] (base pre-offset); dst: [npix][256] bf16
__global__ __launch_bounds__(256) void k_lnT(const float* __restrict__ src,
                                             const float* __restrict__ lw, const float* __restrict__ lb,
                                             u16* __restrict__ dst,
                                             float* __restrict__ muo, float* __restrict__ rso) {
  __shared__ u16 tile[256][72];
  __shared__ float ps[4][64], ps2[4][64], smu[64], srs[64];
  int tid = threadIdx.x;
  int pix0 = blockIdx.x*64;
  int bfold = pix0 >> 14, hw0 = pix0 & 16383;
  const float* sb = src + (size_t)bfold*CHW + hw0;
  {
    int p = tid & 63, part = tid >> 6;
    float s = 0.f, s2 = 0.f;
    for (int c = part*64; c < part*64 + 64; ++c) {
      float v = sb[(size_t)c*HW + p];
      s += v; s2 += v*v;
      tile[c][p] = f2b(v);
    }
    ps[part][p] = s; ps2[part][p] = s2;
  }
  __syncthreads();
  if (tid < 64) {
    float s  = ps[0][tid]+ps[1][tid]+ps[2][tid]+ps[3][tid];
    float s2 = ps2[0][tid]+ps2[1][tid]+ps2[2][tid]+ps2[3][tid];
    float m = s*(1.f/256.f);
    float var = fmaxf(s2*(1.f/256.f) - m*m, 0.f);
    float r = rsqrtf(var + 1e-6f);
    smu[tid] = m; srs[tid] = r;
    if (muo) { muo[pix0+tid] = m; rso[pix0+tid] = r; }
  }
  __syncthreads();
  {
    int p = tid >> 2, cp = tid & 3;
    float m = smu[p], r = srs[p];
    ushort buf[64];
#pragma unroll
    for (int j = 0; j < 64; ++j) {
      int c = cp*64 + j;
      float v = (b2f(tile[c][p]) - m)*r*lw[c] + lb[c];
      buf[j] = f2b(v);
    }
    u16* dp = dst + (size_t)(pix0+p)*256 + cp*64;
#pragma unroll
    for (int qq = 0; qq < 8; ++qq)
      *(uint4*)(dp + qq*8) = *(const uint4*)(&buf[qq*8]);
  }
}

// ---------------- MFMA GEMM: out[p][o] = bias[o] + sum_k A[p][k]*Bw[o][k] -------
#define EPI_PM  0   // bf16 pixel-major out
#define EPI_CMN 1   // bf16 channel-major out + per-head (o-tile) L2 normalize
#define EPI_Y1  2   // fp32 channel-major out + resid (y)
#define EPI_OUT 3   // fp32 channel-major out + y1 + LN2(y1)

template<int EPI, bool AV>
__global__ __launch_bounds__(256) void k_mm(
    const u16* __restrict__ A, int ldA,
    const u16* __restrict__ Bw, int ldB,
    const float* __restrict__ bias, int biasN,
    int K,
    void* __restrict__ outp, int ldOut,
    const float* __restrict__ resid,
    const float* __restrict__ mu, const float* __restrict__ rs,
    const float* __restrict__ lnw, const float* __restrict__ lnb)
{
  __shared__ char smem[32768];
  __shared__ float nbuf[4][64];
  __shared__ float sLn[64];
  u16* sA = (u16*)smem;
  u16* sB = (u16*)(smem + 16384);

  const int tid = threadIdx.x, lane = tid & 63, w = tid >> 6;
  const int wr = w >> 1, wc = w & 1;
  const int p0 = blockIdx.x * 128;
  const int o0 = blockIdx.y * 128;
  const int bfold = p0 >> 14;
  int acol0 = 0, colbase = o0;
  const u16* Bbase = Bw;
  if (AV) {
    int h = blockIdx.z;
    acol0 = h*128;
    colbase = h*128;
    Bbase = Bw + ((size_t)(bfold*2 + h))*16384;
  }

  f32x4 acc[4][4];
#pragma unroll
  for (int i = 0; i < 4; ++i)
#pragma unroll
    for (int j = 0; j < 4; ++j) acc[i][j] = (f32x4){0.f,0.f,0.f,0.f};

  const int r8 = lane >> 3, cl = lane & 7;
  for (int kt = 0; kt < K; kt += 64) {
#pragma unroll
    for (int i = 0; i < 4; ++i) {
      int rowb = w*32 + i*8;
      int row = rowb + r8;
      int chk = cl ^ (row & 7);
      gload16(A + (size_t)(p0+row)*ldA + acol0 + kt + chk*8, sA + rowb*64);
    }
#pragma unroll
    for (int i = 0; i < 4; ++i) {
      int rowb = w*32 + i*8;
      int row = rowb + r8;
      int chk = cl ^ (row & 7);
      gload16(Bbase + (size_t)(o0+row)*ldB + kt + chk*8, sB + rowb*64);
    }
    asm volatile("s_waitcnt vmcnt(0)" ::: "memory");
    __syncthreads();
#pragma unroll
    for (int kk = 0; kk < 2; ++kk) {
      bf16x8 af[4], bfr[4];
#pragma unroll
      for (int mi = 0; mi < 4; ++mi) {
        int row = wr*64 + mi*16 + (lane & 15);
        int cidx = (kk*4 + (lane >> 4)) ^ (row & 7);
        af[mi] = *(const bf16x8*)(sA + row*64 + cidx*8);
      }
#pragma unroll
      for (int ni = 0; ni < 4; ++ni) {
        int row = wc*64 + ni*16 + (lane & 15);
        int cidx = (kk*4 + (lane >> 4)) ^ (row & 7);
        bfr[ni] = *(const bf16x8*)(sB + row*64 + cidx*8);
      }
#pragma unroll
      for (int mi = 0; mi < 4; ++mi)
#pragma unroll
        for (int ni = 0; ni < 4; ++ni)
          acc[mi][ni] = __builtin_amdgcn_mfma_f32_16x16x32_bf16(af[mi], bfr[ni], acc[mi][ni], 0, 0, 0);
    }
    __syncthreads();
  }

  float bo[4];
#pragma unroll
  for (int ni = 0; ni < 4; ++ni) {
    int og = o0 + wc*64 + ni*16 + (lane & 15);
    bo[ni] = (bias != nullptr && og < biasN) ? bias[og] : 0.f;
  }

  if (EPI == EPI_PM) {
    u16 (*Lt)[72] = (u16(*)[72])smem;
    u16* ow = (u16*)outp;
    for (int H = 0; H < 2; ++H) {
      if (wc == H) {
#pragma unroll
        for (int mi = 0; mi < 4; ++mi)
#pragma unroll
          for (int ni = 0; ni < 4; ++ni)
#pragma unroll
            for (int r = 0; r < 4; ++r) {
              int pl = wr*64 + mi*16 + (lane>>4)*4 + r;
              int ol = ni*16 + (lane & 15);
              Lt[pl][ol] = f2b(acc[mi][ni][r] + bo[ni]);
            }
      }
      __syncthreads();
      {
        int p = tid >> 1, hs = tid & 1;
        size_t base = (size_t)(p0+p)*ldOut + colbase + H*64 + hs*32;
#pragma unroll
        for (int qq = 0; qq < 4; ++qq)
          *(uint4*)(ow + base + qq*8) = *(const uint4*)(&Lt[p][hs*32 + qq*8]);
      }
      __syncthreads();
    }
  } else {
    u16 (*Lt)[72] = (u16(*)[72])smem;
    for (int H = 0; H < 2; ++H) {
      if (wr == H) {
#pragma unroll
        for (int mi = 0; mi < 4; ++mi)
#pragma unroll
          for (int ni = 0; ni < 4; ++ni)
#pragma unroll
            for (int r = 0; r < 4; ++r) {
              int ol = wc*64 + ni*16 + (lane & 15);
              int pl = mi*16 + (lane>>4)*4 + r;
              Lt[ol][pl] = f2b(acc[mi][ni][r] + bo[ni]);
            }
      }
      __syncthreads();
      if (EPI == EPI_CMN) {
        {
          int p = tid & 63, part = tid >> 6;
          float s = 0.f;
#pragma unroll 8
          for (int oo = part*32; oo < part*32 + 32; ++oo) {
            float v = b2f(Lt[oo][p]); s += v*v;
          }
          nbuf[part][p] = s;
        }
        __syncthreads();
        if (tid < 64) {
          float t2 = nbuf[0][tid]+nbuf[1][tid]+nbuf[2][tid]+nbuf[3][tid];
          sLn[tid] = 1.f / fmaxf(sqrtf(t2), 1e-12f);
        }
        __syncthreads();
      }
      {
        int o = tid >> 1, hs = tid & 1;
        int hw0 = p0 & 16383;
        size_t addr = ((size_t)(bfold*ldOut + o0 + o))*HW + hw0 + H*64 + hs*32;
        if (EPI == EPI_CMN) {
          u16* ow = (u16*)outp;
          ushort tb[32];
#pragma unroll
          for (int j = 0; j < 32; ++j)
            tb[j] = f2b(b2f(Lt[o][hs*32+j]) * sLn[hs*32+j]);
#pragma unroll
          for (int qq = 0; qq < 4; ++qq)
            *(uint4*)(ow + addr + qq*8) = *(const uint4*)(&tb[qq*8]);
        } else if (EPI == EPI_Y1) {
          float* of = (float*)outp;
#pragma unroll
          for (int j = 0; j < 32; ++j)
            of[addr + j] = b2f(Lt[o][hs*32+j]) + resid[addr + j];
        } else if (EPI == EPI_OUT) {
          float* of = (float*)outp;
          float wgt = lnw[o0+o], bb = lnb[o0+o];
#pragma unroll
          for (int j = 0; j < 32; ++j) {
            int pg = (p0 & 16383) + H*64 + hs*32 + j;
            float yv = resid[addr + j];
            of[addr + j] = b2f(Lt[o][hs*32+j]) + yv + (yv - mu[pg])*rs[pg]*wgt + bb;
          }
        }
      }
      __syncthreads();
    }
  }
}

// ---------------- QK^T: attn_p[bh*32+s][ci][cj] = sum_{512 p} q k ---------------
__global__ __launch_bounds__(256) void k_qk(const u16* __restrict__ q, const u16* __restrict__ k,
                                            float* __restrict__ ap)
{
  __shared__ char smem[32768];
  u16* sA = (u16*)smem;
  u16* sB = (u16*)(smem + 16384);
  const int tid = threadIdx.x, lane = tid & 63, w = tid >> 6;
  const int wr = w >> 1, wc = w & 1;
  const int s = blockIdx.x, bh = blockIdx.y;
  const int bfold = bh >> 1, h = bh & 1;
  const u16* qb = q + ((size_t)(bfold*256 + h*128))*HW + s*512;
  const u16* kb = k + ((size_t)(bfold*256 + h*128))*HW + s*512;

  f32x4 acc[4][4];
#pragma unroll
  for (int i = 0; i < 4; ++i)
#pragma unroll
    for (int j = 0; j < 4; ++j) acc[i][j] = (f32x4){0.f,0.f,0.f,0.f};

  const int r8 = lane >> 3, cl = lane & 7;
  for (int kt = 0; kt < 512; kt += 64) {
#pragma unroll
    for (int i = 0; i < 4; ++i) {
      int rowb = w*32 + i*8;
      int row = rowb + r8;
      int chk = cl ^ (row & 7);
      gload16(qb + (size_t)row*HW + kt + chk*8, sA + rowb*64);
      gload16(kb + (size_t)row*HW + kt + chk*8, sB + rowb*64);
    }
    asm volatile("s_waitcnt vmcnt(0)" ::: "memory");
    __syncthreads();
#pragma unroll
    for (int kk = 0; kk < 2; ++kk) {
      bf16x8 af[4], bfr[4];
#pragma unroll
      for (int mi = 0; mi < 4; ++mi) {
        int row = wr*64 + mi*16 + (lane & 15);
        int cidx = (kk*4 + (lane >> 4)) ^ (row & 7);
        af[mi] = *(const bf16x8*)(sA + row*64 + cidx*8);
      }
#pragma unroll
      for (int ni = 0; ni < 4; ++ni) {
        int row = wc*64 + ni*16 + (lane & 15);
        int cidx = (kk*4 + (lane >> 4)) ^ (row & 7);
        bfr[ni] = *(const bf16x8*)(sB + row*64 + cidx*8);
      }
#pragma unroll
      for (int mi = 0; mi < 4; ++mi)
#pragma unroll
        for (int ni = 0; ni < 4; ++ni)
          acc[mi][ni] = __builtin_amdgcn_mfma_f32_16x16x32_bf16(af[mi], bfr[ni], acc[mi][ni], 0, 0, 0);
    }
    __syncthreads();
  }
  float* out = ap + (((size_t)(bh*32 + s)) << 14);
#pragma unroll
  for (int mi = 0; mi < 4; ++mi)
#pragma unroll
    for (int ni = 0; ni < 4; ++ni)
#pragma unroll
      for (int r = 0; r < 4; ++r) {
        int ci = wr*64 + mi*16 + (lane>>4)*4 + r;
        int cj = wc*64 + ni*16 + (lane & 15);
        out[(size_t)ci*128 + cj] = acc[mi][ni][r];
      }
}

// ---------------- reduce splits + scale + softmax -> bf16 attn ------------------
__global__ __launch_bounds__(256) void k_sm(const float* __restrict__ ap, const float* __restrict__ temp,
                                            u16* __restrict__ attnb) {
  int tid = threadIdx.x, lane = tid & 63, wrow = tid >> 6;
  int row = blockIdx.x*4 + wrow;           // 0..511
  int bh = row >> 7, ci = row & 127;
  int h = bh & 1;
  float v0 = 0.f, v1 = 0.f;
  for (int s = 0; s < 32; ++s) {
    const float* pp = ap + (((size_t)(bh*32 + s)) << 14) + (size_t)ci*128;
    v0 += pp[lane]; v1 += pp[lane + 64];
  }
  float scale = 0.1f / (1.f + expf(-temp[h]));
  float m = fmaxf(v0, v1);
  for (int d = 1; d < 64; d <<= 1) m = fmaxf(m, __shfl_xor(m, d));
  float e0 = expf((v0 - m)*scale), e1 = expf((v1 - m)*scale);
  float ssum = e0 + e1;
  for (int d = 1; d < 64; d <<= 1) ssum += __shfl_xor(ssum, d);
  float inv = 1.f/ssum;
  attnb[(size_t)bh*HW + ci*128 + lane]      = f2b(e0*inv);
  attnb[(size_t)bh*HW + ci*128 + lane + 64] = f2b(e1*inv);
}

// ---------------- depthwise 3x3 + GELU gate (pixel-major) -----------------------
__global__ void k_dwgate(const u16* __restrict__ t,
                         const float* __restrict__ dww, const float* __restrict__ dwb,
                         u16* __restrict__ g) {
  int c = blockIdx.x*64 + threadIdx.x;     // 0..703
  int wpx = blockIdx.y*4 + threadIdx.y;
  int hpx = blockIdx.z;
  size_t gaddr = ((size_t)(hpx*128 + wpx))*704 + c;
  if (c >= 680) { g[gaddr] = 0; return; }
  float wa[9], wb9[9];
#pragma unroll
  for (int i = 0; i < 9; ++i) { wa[i] = dww[(size_t)c*9 + i]; wb9[i] = dww[(size_t)(c+680)*9 + i]; }
  float d1 = dwb[c], d2 = dwb[c + 680];
#pragma unroll
  for (int dy = -1; dy <= 1; ++dy) {
    int yy = hpx + dy; if (yy < 0 || yy >= 128) continue;
#pragma unroll
    for (int dx = -1; dx <= 1; ++dx) {
      int xx = wpx + dx; if (xx < 0 || xx >= 128) continue;
      const u16* tp = t + ((size_t)(yy*128 + xx))*1408;
      int ki = (dy+1)*3 + (dx+1);
      d1 += b2f(tp[c])*wa[ki];
      d2 += b2f(tp[c+680])*wb9[ki];
    }
  }
  float u = d1;
  float gl = 0.5f*u*(1.f + tanhf(0.7978845608028654f*(u + 0.044715f*u*u*u)));
  g[gaddr] = f2b(gl*d2);
}

// -------------------------------------------------------------------------------
extern "C" void kernel_launch(void* const* d_in, const int* in_sizes, int n_in,
                              void* d_out, int out_size, void* d_ws, size_t ws_size,
                              hipStream_t stream) {
  const float* x     = (const float*)d_in[0];
  const float* y     = (const float*)d_in[1];
  const float* n1w   = (const float*)d_in[2];
  const float* n1b   = (const float*)d_in[3];
  const float* q_w   = (const float*)d_in[4];
  const float* q_b   = (const float*)d_in[5];
  const float* kv_w  = (const float*)d_in[6];
  const float* kv_b  = (const float*)d_in[7];
  const float* proj_w= (const float*)d_in[8];
  const float* proj_b= (const float*)d_in[9];
  const float* temp  = (const float*)d_in[10];
  const float* n2w   = (const float*)d_in[11];
  const float* n2b   = (const float*)d_in[12];
  const float* c1w   = (const float*)d_in[13];
  const float* c1b   = (const float*)d_in[14];
  const float* dww   = (const float*)d_in[15];
  const float* dwb   = (const float*)d_in[16];
  const float* c2w   = (const float*)d_in[17];
  const float* c2b   = (const float*)d_in[18];
  float* outf = (float*)d_out;

  const size_t MB = 1u << 20;
  // pair phase
  const size_t OFF_XLN = 0;            // 16.78 MB  (later: ao; FFN: y1ln 8.39 + mu/rs)
  const size_t OFF_YLN = 17*MB;        // 16.78 MB
  const size_t OFF_Q   = 34*MB;        // 16.78 MB  (FFN: t spans 34..80.14)
  const size_t OFF_K   = 51*MB;
  const size_t OFF_V   = 68*MB;
  const size_t OFF_AP  = 85*MB;        // 8.39 MB fp32 partials
  const size_t OFF_AB  = 93*MB + 512*1024;  // 131 KB bf16 attn
  const size_t OFF_W   = 94*MB;        // 1.54 MB weights
  // FFN phase
  const size_t OFF_Y1L = 0;            // 8.39 MB
  const size_t OFF_MU2 = 9*MB;
  const size_t OFF_RS2 = 9*MB + 262144;
  const size_t OFF_G   = 10*MB;        // 23.07 MB -> ends 33.07
  const size_t OFF_T   = 34*MB;        // 46.14 MB -> ends 80.14
  const size_t NEED = OFF_W + 1605632;
  if (ws_size < NEED) return;

  char* wsb = (char*)d_ws;
  u16* xln = (u16*)(wsb + OFF_XLN);
  u16* yln = (u16*)(wsb + OFF_YLN);
  u16* qs  = (u16*)(wsb + OFF_Q);
  u16* ks  = (u16*)(wsb + OFF_K);
  u16* vs  = (u16*)(wsb + OFF_V);
  float* ap = (float*)(wsb + OFF_AP);
  u16* attnb = (u16*)(wsb + OFF_AB);
  u16* qwB = (u16*)(wsb + OFF_W);
  u16* kvwB = qwB + 65536;
  u16* pjwB = kvwB + 131072;
  u16* c1wB = pjwB + 65536;
  u16* c2wB = c1wB + 360448;
  u16* aos = xln;                      // reuse
  u16* y1ln = (u16*)(wsb + OFF_Y1L);
  float* mu2 = (float*)(wsb + OFF_MU2);
  float* rs2 = (float*)(wsb + OFF_RS2);
  u16* gbuf = (u16*)(wsb + OFF_G);
  u16* tbuf = (u16*)(wsb + OFF_T);

  // weights -> bf16 (padded)
  k_w2b<<<256, 256, 0, stream>>>(q_w, qwB, 256, 256, 256);
  k_w2b<<<512, 256, 0, stream>>>(kv_w, kvwB, 512, 256, 256);
  k_w2b<<<256, 256, 0, stream>>>(proj_w, pjwB, 256, 256, 256);
  k_w2b<<<1408, 256, 0, stream>>>(c1w, c1wB, 1360, 256, 256);
  k_w2b<<<704, 256, 0, stream>>>(c2w, c2wB, 256, 680, 704);

  for (int pb = 0; pb < 2; ++pb) {
    size_t pbase = (size_t)pb*2*CHW;
    // LN1(x), LN1(y) -> pixel-major bf16
    k_lnT<<<512, 256, 0, stream>>>(x + pbase, n1w, n1b, xln, nullptr, nullptr);
    k_lnT<<<512, 256, 0, stream>>>(y + pbase, n1w, n1b, yln, nullptr, nullptr);
    // q, k (channel-major + L2 norm), v (pixel-major)
    k_mm<EPI_CMN, false><<<dim3(256,2), 256, 0, stream>>>(xln, 256, qwB, 256, q_b, 256, 256,
        qs, 256, nullptr, nullptr, nullptr, nullptr, nullptr);
    k_mm<EPI_CMN, false><<<dim3(256,2), 256, 0, stream>>>(yln, 256, kvwB, 256, kv_b, 256, 256,
        ks, 256, nullptr, nullptr, nullptr, nullptr, nullptr);
    k_mm<EPI_PM, false><<<dim3(256,2), 256, 0, stream>>>(yln, 256, kvwB + 256*256, 256, kv_b + 256, 256, 256,
        vs, 256, nullptr, nullptr, nullptr, nullptr, nullptr);
    // attn
    k_qk<<<dim3(32,4), 256, 0, stream>>>(qs, ks, ap);
    k_sm<<<128, 256, 0, stream>>>(ap, temp, attnb);
    // ao = attn @ v (pixel-major)
    k_mm<EPI_PM, true><<<dim3(256,1,2), 256, 0, stream>>>(vs, 256, attnb, 128, nullptr, 0, 128,
        aos, 256, nullptr, nullptr, nullptr, nullptr, nullptr);
    // y1 = y + proj(ao) -> d_out fp32 channel-major
    k_mm<EPI_Y1, false><<<dim3(256,2), 256, 0, stream>>>(aos, 256, pjwB, 256, proj_b, 256, 256,
        outf + pbase, 256, y + pbase, nullptr, nullptr, nullptr, nullptr);
  }

  for (int b = 0; b < 4; ++b) {
    float* y1b = outf + (size_t)b*CHW;
    // LN2(y1) -> pixel-major bf16 + stats
    k_lnT<<<256, 256, 0, stream>>>(y1b, n2w, n2b, y1ln, mu2, rs2);
    // t = conv1(LN2(y1))  pixel-major [16384][1408]
    k_mm<EPI_PM, false><<<dim3(128,11), 256, 0, stream>>>(y1ln, 256, c1wB, 256, c1b, 1360, 256,
        tbuf, 1408, nullptr, nullptr, nullptr, nullptr, nullptr);
    // g = gelu(dw1(t1)) * dw2(t2)  pixel-major [16384][704]
    k_dwgate<<<dim3(11,32,128), dim3(64,4,1), 0, stream>>>(tbuf, dww, dwb, gbuf);
    // out = y1 + LN2(y1) + conv2(g)
    k_mm<EPI_OUT, false><<<dim3(128,2), 256, 0, stream>>>(gbuf, 704, c2wB, 704, c2b, 256, 704,
        y1b, 256, y1b, mu2, rs2, n2w, n2b);
  }
}